// Round 1
// baseline (2064.375 us; speedup 1.0000x reference)
//
#include <hip/hip_runtime.h>

#define NB 256        // batch B
#define K1 4097       // K+1
#define NROWS 1000000 // N (memory bank rows)
#define DD 128        // D

static constexpr float  INV_T = 1.0f / 0.07f;
static constexpr double CNT   = (double)NB * (double)K1;   // elements per view
static constexpr double NOUT  = (double)NROWS;             // outputSize

// ---------------------------------------------------------------------------
// zero the two double accumulators in workspace (ws is poisoned 0xAA pre-launch)
__global__ void zero_ws_kernel(double* ws) {
    if (threadIdx.x < 2) ws[threadIdx.x] = 0.0;
}

// ---------------------------------------------------------------------------
// For each (b,k): j = (k==0 ? y[b] : idx[b,k])
//   out1[b,k] = exp(dot(mem2[j], v1[b]) / T)   (unnormalized)
//   out2[b,k] = exp(dot(mem1[j], v2[b]) / T)
// Block = 256 threads = 4 waves; each wave handles 16 consecutive k.
// Within a wave: lanes 0-31 process view1 (bank mem2, vec v1), lanes 32-63
// view2 (bank mem1, vec v2). Each half-wave covers one 512B row via float4.
__global__ __launch_bounds__(256) void gather_exp_kernel(
    const float* __restrict__ v1, const float* __restrict__ v2,
    const float* __restrict__ mem1, const float* __restrict__ mem2,
    const int* __restrict__ y, const int* __restrict__ idx,
    float* __restrict__ out1, float* __restrict__ out2, double* __restrict__ ws)
{
    const int b     = blockIdx.x;
    const int chunk = blockIdx.y;
    const int wave  = threadIdx.x >> 6;
    const int lane  = threadIdx.x & 63;
    const int half  = lane >> 5;    // 0: view1, 1: view2
    const int l32   = lane & 31;

    const float*  vsrc = half ? (v2 + b * DD) : (v1 + b * DD);
    const float*  bank = half ? mem1 : mem2;
    float*        outp = half ? out2 : out1;

    const float4 vr = ((const float4*)vsrc)[l32];

    double s = 0.0;
    const int kbase = chunk * 64 + wave * 16;
    for (int i = 0; i < 16; ++i) {
        const int k = kbase + i;
        if (k >= K1) break;
        const int j = (k == 0) ? y[b] : idx[b * K1 + k];
        const float4 m = ((const float4*)(bank + (long long)j * DD))[l32];
        float p = m.x * vr.x + m.y * vr.y + m.z * vr.z + m.w * vr.w;
        // reduce within each 32-lane half (xor offsets <32 stay in-half)
        p += __shfl_xor(p, 16, 64);
        p += __shfl_xor(p,  8, 64);
        p += __shfl_xor(p,  4, 64);
        p += __shfl_xor(p,  2, 64);
        p += __shfl_xor(p,  1, 64);
        const float e = expf(p * INV_T);
        if (l32 == 0) {
            outp[b * K1 + k] = e;
            s += (double)e;
        }
    }

    __shared__ double sh[2][4];
    if (l32 == 0) sh[half][wave] = s;
    __syncthreads();
    if (threadIdx.x == 0) {
        atomicAdd(ws + 0, sh[0][0] + sh[0][1] + sh[0][2] + sh[0][3]);
        atomicAdd(ws + 1, sh[1][0] + sh[1][1] + sh[1][2] + sh[1][3]);
    }
}

// ---------------------------------------------------------------------------
// out[i] /= Z  with Z = (sum / CNT) * NOUT, per view
__global__ __launch_bounds__(256) void scale_kernel(
    float* __restrict__ out, const double* __restrict__ ws)
{
    const float s1 = (float)(1.0 / (ws[0] * (NOUT / CNT)));
    const float s2 = (float)(1.0 / (ws[1] * (NOUT / CNT)));
    const int total = 2 * NB * K1;
    const int view1 = NB * K1;
    for (int i = blockIdx.x * blockDim.x + threadIdx.x; i < total;
         i += gridDim.x * blockDim.x) {
        out[i] *= (i < view1) ? s1 : s2;
    }
}

// ---------------------------------------------------------------------------
// float4 grid-stride copy (new_memory = old memory, before scatter update)
__global__ __launch_bounds__(256) void copy_kernel(
    const float4* __restrict__ src, float4* __restrict__ dst, long long n4)
{
    long long i = (long long)blockIdx.x * blockDim.x + threadIdx.x;
    const long long stride = (long long)gridDim.x * blockDim.x;
    for (; i < n4; i += stride) dst[i] = src[i];
}

// ---------------------------------------------------------------------------
// pos = 0.5*mem[y[b]] + 0.5*v[b]; pos /= ||pos||; new_mem[y[b]] = pos
// One wave per b; lane holds float2 (64*2 = 128 = D).
// Duplicate y: numpy last-occurrence-wins -> skip if a later b has same y.
__global__ __launch_bounds__(64) void update_kernel(
    const float* __restrict__ v1, const float* __restrict__ v2,
    const float* __restrict__ mem1, const float* __restrict__ mem2,
    const int* __restrict__ y,
    float* __restrict__ nm1, float* __restrict__ nm2)
{
    const int b    = blockIdx.x;
    const int lane = threadIdx.x;
    const int yb   = y[b];

    bool skip = false;
    for (int b2 = b + 1; b2 < NB; ++b2) skip |= (y[b2] == yb);
    if (skip) return;

    // view 1
    {
        float2 m = ((const float2*)(mem1 + (long long)yb * DD))[lane];
        float2 v = ((const float2*)(v1 + b * DD))[lane];
        float2 p = make_float2(0.5f * (m.x + v.x), 0.5f * (m.y + v.y));
        float ss = p.x * p.x + p.y * p.y;
        for (int off = 32; off; off >>= 1) ss += __shfl_xor(ss, off, 64);
        const float inv = 1.0f / sqrtf(ss);
        p.x *= inv; p.y *= inv;
        ((float2*)(nm1 + (long long)yb * DD))[lane] = p;
    }
    // view 2
    {
        float2 m = ((const float2*)(mem2 + (long long)yb * DD))[lane];
        float2 v = ((const float2*)(v2 + b * DD))[lane];
        float2 p = make_float2(0.5f * (m.x + v.x), 0.5f * (m.y + v.y));
        float ss = p.x * p.x + p.y * p.y;
        for (int off = 32; off; off >>= 1) ss += __shfl_xor(ss, off, 64);
        const float inv = 1.0f / sqrtf(ss);
        p.x *= inv; p.y *= inv;
        ((float2*)(nm2 + (long long)yb * DD))[lane] = p;
    }
}

// ---------------------------------------------------------------------------
extern "C" void kernel_launch(void* const* d_in, const int* in_sizes, int n_in,
                              void* d_out, int out_size, void* d_ws, size_t ws_size,
                              hipStream_t stream) {
    const float* v1   = (const float*)d_in[0];
    const float* v2   = (const float*)d_in[1];
    const float* mem1 = (const float*)d_in[2];
    const float* mem2 = (const float*)d_in[3];
    const int*   y    = (const int*)d_in[4];
    const int*   idx  = (const int*)d_in[5];

    float* out  = (float*)d_out;
    float* out1 = out;                                   // [B, K+1]
    float* out2 = out + (size_t)NB * K1;                 // [B, K+1]
    float* nm1  = out + (size_t)2 * NB * K1;             // [N, D]
    float* nm2  = nm1 + (size_t)NROWS * DD;              // [N, D]
    double* ws  = (double*)d_ws;

    hipLaunchKernelGGL(zero_ws_kernel, dim3(1), dim3(64), 0, stream, ws);

    dim3 ggrid(NB, (K1 + 63) / 64);
    hipLaunchKernelGGL(gather_exp_kernel, ggrid, dim3(256), 0, stream,
                       v1, v2, mem1, mem2, y, idx, out1, out2, ws);

    hipLaunchKernelGGL(scale_kernel, dim3(2048), dim3(256), 0, stream, out, ws);

    const long long n4 = (long long)NROWS * DD / 4;
    hipLaunchKernelGGL(copy_kernel, dim3(16384), dim3(256), 0, stream,
                       (const float4*)mem1, (float4*)nm1, n4);
    hipLaunchKernelGGL(copy_kernel, dim3(16384), dim3(256), 0, stream,
                       (const float4*)mem2, (float4*)nm2, n4);

    hipLaunchKernelGGL(update_kernel, dim3(NB), dim3(64), 0, stream,
                       v1, v2, mem1, mem2, y, nm1, nm2);
}